// Round 3
// baseline (12965.085 us; speedup 1.0000x reference)
//
#include <hip/hip_runtime.h>

#define T_ 1000

__device__ __forceinline__ float sigf(float x) { return 1.0f / (1.0f + __expf(-x)); }
__device__ __forceinline__ float tanh_fast(float x) { return 1.0f - 2.0f / (1.0f + __expf(2.0f * x)); }
__device__ __forceinline__ float dot4(float4 a, float4 b) {
  return a.x * b.x + a.y * b.y + a.z * b.z + a.w * b.w;
}
__device__ __forceinline__ unsigned short f2bf(float f) {
  unsigned u = __float_as_uint(f);
  u = (u + 0x7fffu + ((u >> 16) & 1u)) >> 16;  // RNE
  return (unsigned short)u;
}
__device__ __forceinline__ float bf2f(unsigned short h) {
  return __uint_as_float(((unsigned)h) << 16);
}
__device__ __forceinline__ float4 bf4_to_f4(ushort4 u) {
  float4 r;
  r.x = bf2f(u.x); r.y = bf2f(u.y); r.z = bf2f(u.z); r.w = bf2f(u.w);
  return r;
}

__global__ void bail_kernel(float* out, int n) {
  for (int i = threadIdx.x; i < n; i += 256) out[i] = 0.0f;
}

// ---------------- Layer-0 recurrence with fused LayerNorm, 1 block per (row,dir) ----------------
// 512 threads: thread (j = tid&127, p = tid>>7) computes all 4 gates of unit j over
// k-quarter p. Wave 2 (p==1, j<64) owns raw-x load + LayerNorm + x4 staging.
__global__ __launch_bounds__(512, 2) void rec0_kernel(
    const float* __restrict__ x,
    const float* __restrict__ ln_g, const float* __restrict__ ln_b,
    const float* __restrict__ Wih_f, const float* __restrict__ Whh_f,
    const float* __restrict__ bih_f, const float* __restrict__ bhh_f,
    const float* __restrict__ Wih_b, const float* __restrict__ Whh_b,
    const float* __restrict__ bih_b, const float* __restrict__ bhh_b,
    float* __restrict__ h0) {
  const int tid = threadIdx.x;
  const int j = tid & 127;
  const int p = tid >> 7;
  const int brow = blockIdx.x & 127;
  const int dir = blockIdx.x >> 7;
  const float* __restrict__ Wih = dir ? Wih_b : Wih_f;
  const float* __restrict__ Whh = dir ? Whh_b : Whh_f;
  const float* __restrict__ bih = dir ? bih_b : bih_f;
  const float* __restrict__ bhh = dir ? bhh_b : bhh_f;

  float4 wh[4][8];
  float4 wi[4][3];
#pragma unroll
  for (int g = 0; g < 4; ++g) {
    const int row = g * 128 + j;
    const float4* wr = (const float4*)(Whh + row * 128 + p * 32);
#pragma unroll
    for (int f = 0; f < 8; ++f) wh[g][f] = wr[f];
    const float* xr = Wih + row * 40;
#pragma unroll
    for (int f = 0; f < 3; ++f) {
      const int k0 = p * 12 + f * 4;
      float4 tv;
      tv.x = (k0 + 0 < 40) ? xr[k0 + 0] : 0.0f;
      tv.y = (k0 + 1 < 40) ? xr[k0 + 1] : 0.0f;
      tv.z = (k0 + 2 < 40) ? xr[k0 + 2] : 0.0f;
      tv.w = (k0 + 3 < 40) ? xr[k0 + 3] : 0.0f;
      wi[g][f] = tv;
    }
  }
  const float bias = bih[p * 128 + j] + bhh[p * 128 + j];
  const float b0 = (p == 0) ? bias : 0.0f;
  const float b1 = (p == 1) ? bias : 0.0f;
  const float b2 = (p == 2) ? bias : 0.0f;
  const float b3 = (p == 3) ? bias : 0.0f;

  __shared__ float4 h4[32];      // h state, 128 f
  __shared__ float4 x4[12];      // normalized x row padded to 48 f
  __shared__ float4 part4[384];  // partials from p=1..3

  // LN constants for the loader wave
  float gj = 0.0f, bj = 0.0f;
  if (p == 1 && j < 40) { gj = ln_g[j]; bj = ln_b[j]; }

  if (tid < 32) h4[tid] = make_float4(0.f, 0.f, 0.f, 0.f);
  if (tid >= 40 && tid < 48) ((float*)x4)[tid] = 0.0f;  // pad tail
  __syncthreads();

  const long xbase = (long)brow * T_ * 40;
  float xreg = 0.0f;  // raw x for the NEXT-next step (lanes j<40 of wave 2 only)
  if (p == 1 && j < 64) {
    // LN of first step's row
    const long tA = dir ? (T_ - 1) : 0;
    float v = (j < 40) ? x[xbase + tA * 40 + j] : 0.0f;
    float s1 = v, s2 = v * v;
#pragma unroll
    for (int m = 32; m; m >>= 1) {
      s1 += __shfl_xor(s1, m, 64);
      s2 += __shfl_xor(s2, m, 64);
    }
    const float mu = s1 * (1.0f / 40.0f);
    const float var = s2 * (1.0f / 40.0f) - mu * mu;
    const float rs = rsqrtf(var + 1e-5f);
    if (j < 40) ((float*)x4)[j] = (v - mu) * rs * gj + bj;
    // prefetch raw row for step 1
    const long tB = dir ? (T_ - 2) : 1;
    if (j < 40) xreg = x[xbase + tB * 40 + j];
  }
  float c = 0.0f;
  __syncthreads();

  const long hbase = (long)brow * T_ * 256;
  for (int t = 0; t < T_; ++t) {
    const int t_eff = dir ? (T_ - 1 - t) : t;
    float a0 = b0, a1 = b1, a2 = b2, a3 = b3;
#pragma unroll
    for (int f = 0; f < 3; ++f) {
      const float4 xv = x4[p * 3 + f];
      a0 += dot4(xv, wi[0][f]);
      a1 += dot4(xv, wi[1][f]);
      a2 += dot4(xv, wi[2][f]);
      a3 += dot4(xv, wi[3][f]);
    }
#pragma unroll
    for (int f = 0; f < 8; ++f) {
      const float4 hv = h4[p * 8 + f];
      a0 += dot4(hv, wh[0][f]);
      a1 += dot4(hv, wh[1][f]);
      a2 += dot4(hv, wh[2][f]);
      a3 += dot4(hv, wh[3][f]);
    }
    if (p) part4[(p - 1) * 128 + j] = make_float4(a0, a1, a2, a3);
    __syncthreads();
    if (!p) {
      const float4 q0 = part4[j], q1 = part4[128 + j], q2 = part4[256 + j];
      a0 += q0.x + q1.x + q2.x;
      a1 += q0.y + q1.y + q2.y;
      a2 += q0.z + q1.z + q2.z;
      a3 += q0.w + q1.w + q2.w;
      const float ig = sigf(a0);
      const float fg = sigf(a1);
      const float gg = tanh_fast(a2);
      const float og = sigf(a3);
      c = fg * c + ig * gg;
      const float hv = og * tanh_fast(c);
      ((float*)h4)[j] = hv;
      h0[hbase + (long)t_eff * 256 + dir * 128 + j] = hv;
    } else if (p == 1 && j < 64) {  // whole wave 2: LN next row + prefetch next-next
      if (t + 1 < T_) {
        float v = xreg;  // raw x[t+1] (0 for lanes j>=40)
        float s1 = v, s2 = v * v;
#pragma unroll
        for (int m = 32; m; m >>= 1) {
          s1 += __shfl_xor(s1, m, 64);
          s2 += __shfl_xor(s2, m, 64);
        }
        const float mu = s1 * (1.0f / 40.0f);
        const float var = s2 * (1.0f / 40.0f) - mu * mu;
        const float rs = rsqrtf(var + 1e-5f);
        if (j < 40) ((float*)x4)[j] = (v - mu) * rs * gj + bj;
      }
      if (t + 2 < T_ && j < 40) {
        const long tn = dir ? (T_ - 3 - t) : (t + 2);
        xreg = x[xbase + tn * 40 + j];
      }
    }
    __syncthreads();
  }
}

// ---------------- Layer-1 recurrence, time-chunked; carry h,c in `state`; h1 out bf16 ----------------
__global__ __launch_bounds__(512, 2) void rec1_kernel(
    const float* __restrict__ xw_f, const float* __restrict__ xw_b,
    const float* __restrict__ Whh_f, const float* __restrict__ bih_f, const float* __restrict__ bhh_f,
    const float* __restrict__ Whh_b, const float* __restrict__ bih_b, const float* __restrict__ bhh_b,
    unsigned short* __restrict__ h1b, float* __restrict__ state,
    int Tc, int t0f, int t0b, int first) {
  const int tid = threadIdx.x;
  const int j = tid & 127;
  const int p = tid >> 7;
  const int brow = blockIdx.x & 127;
  const int dir = blockIdx.x >> 7;
  const float* __restrict__ xw = dir ? xw_b : xw_f;
  const float* __restrict__ Whh = dir ? Whh_b : Whh_f;
  const float* __restrict__ bih = dir ? bih_b : bih_f;
  const float* __restrict__ bhh = dir ? bhh_b : bhh_f;
  const int t0 = dir ? t0b : t0f;

  float4 wh[4][8];
#pragma unroll
  for (int g = 0; g < 4; ++g) {
    const float4* wr = (const float4*)(Whh + (g * 128 + j) * 128 + p * 32);
#pragma unroll
    for (int f = 0; f < 8; ++f) wh[g][f] = wr[f];
  }
  const int myrow = p * 128 + j;
  const float bias = bih[myrow] + bhh[myrow];

  __shared__ float4 h4[32];
  __shared__ float4 part4[384];
  float* sblk = state + (long)blockIdx.x * 256;
  float c = 0.0f;
  if (first) {
    if (tid < 32) h4[tid] = make_float4(0.f, 0.f, 0.f, 0.f);
  } else {
    if (tid < 128) ((float*)h4)[tid] = sblk[tid];
    if (!p) c = sblk[128 + j];
  }
  const long gbase = (long)brow * Tc;
  float xreg = xw[(gbase + (dir ? (Tc - 1) : 0)) * 512 + myrow];
  __syncthreads();

  for (int s = 0; s < Tc; ++s) {
    const int tt = dir ? (Tc - 1 - s) : s;
    float xnext = 0.0f;
    if (s + 1 < Tc) {
      const int ttn = dir ? (Tc - 2 - s) : (s + 1);
      xnext = xw[(gbase + ttn) * 512 + myrow];
    }
    float a0 = 0.f, a1 = 0.f, a2 = 0.f, a3 = 0.f;
#pragma unroll
    for (int f = 0; f < 8; ++f) {
      const float4 hv = h4[p * 8 + f];
      a0 += dot4(hv, wh[0][f]);
      a1 += dot4(hv, wh[1][f]);
      a2 += dot4(hv, wh[2][f]);
      a3 += dot4(hv, wh[3][f]);
    }
    const float xin = xreg + bias;
    if (p == 0) a0 += xin;
    else if (p == 1) a1 += xin;
    else if (p == 2) a2 += xin;
    else a3 += xin;
    if (p) part4[(p - 1) * 128 + j] = make_float4(a0, a1, a2, a3);
    __syncthreads();
    if (!p) {
      const float4 q0 = part4[j], q1 = part4[128 + j], q2 = part4[256 + j];
      a0 += q0.x + q1.x + q2.x;
      a1 += q0.y + q1.y + q2.y;
      a2 += q0.z + q1.z + q2.z;
      a3 += q0.w + q1.w + q2.w;
      const float ig = sigf(a0);
      const float fg = sigf(a1);
      const float gg = tanh_fast(a2);
      const float og = sigf(a3);
      c = fg * c + ig * gg;
      const float hv = og * tanh_fast(c);
      ((float*)h4)[j] = hv;
      h1b[((long)brow * T_ + (t0 + tt)) * 256 + dir * 128 + j] = f2bf(hv);
    }
    __syncthreads();
    xreg = xnext;
  }
  if (tid < 128) sblk[tid] = ((float*)h4)[tid];
  if (!p) sblk[128 + j] = c;
}

// ---------------- xw chunk = h0[slice] @ Wih1^T; interleaved micro-tile, padded LDS ----------------
__global__ __launch_bounds__(256, 2) void gemm_xw1(
    const float* __restrict__ h0,
    const float* __restrict__ Wf, const float* __restrict__ Wb,
    float* __restrict__ xwf, float* __restrict__ xwb,
    int Tc, int t0f, int t0b) {
  __shared__ float4 As[1152];  // 128 rows x (8+1 pad) float4
  __shared__ float4 Bs[1152];
  __shared__ int rowbase[128];
  const int tid = threadIdx.x;
  const int tx = tid & 15, ty = tid >> 4;
  const int r0 = blockIdx.x * 128;  // chunk-space row
  const int jt = blockIdx.y;
  const int dir = jt >> 2;
  const float* __restrict__ W = dir ? Wb : Wf;
  float* __restrict__ out = dir ? xwb : xwf;
  const int jbase = (jt & 3) * 128;
  const int t0 = dir ? t0b : t0f;

  if (tid < 128) {
    const int r = r0 + tid;
    const int brow = r / Tc;
    rowbase[tid] = brow * T_ + t0 + (r - brow * Tc);  // h0 row index
  }

  float acc[8][8] = {};
  for (int kk = 0; kk < 8; ++kk) {
    __syncthreads();
#pragma unroll
    for (int i = 0; i < 4; ++i) {
      const int q = tid + i * 256;
      const int row = q >> 3, kq = q & 7;
      As[row * 9 + kq] = *(const float4*)&h0[(long)rowbase[row] * 256 + kk * 32 + kq * 4];
      Bs[row * 9 + kq] = *(const float4*)&W[(jbase + row) * 256 + kk * 32 + kq * 4];
    }
    __syncthreads();
#pragma unroll
    for (int k4 = 0; k4 < 8; ++k4) {
      float4 bv[8];
#pragma unroll
      for (int jj = 0; jj < 8; ++jj) bv[jj] = Bs[(jj * 16 + tx) * 9 + k4];
#pragma unroll
      for (int rr = 0; rr < 8; ++rr) {
        const float4 av = As[(rr * 16 + ty) * 9 + k4];
#pragma unroll
        for (int jj = 0; jj < 8; ++jj) acc[rr][jj] += dot4(av, bv[jj]);
      }
    }
  }
#pragma unroll
  for (int rr = 0; rr < 8; ++rr) {
    const long ob = (long)(r0 + rr * 16 + ty) * 512 + jbase + tx;
#pragma unroll
    for (int jj = 0; jj < 8; ++jj) out[ob + jj * 16] = acc[rr][jj];
  }
}

// ---------------- attention scores: s = tanh(h1 @ W1^T + b1) @ w2 (h1 in bf16) ----------------
__global__ __launch_bounds__(256, 2) void score_kernel(
    const unsigned short* __restrict__ h1b, const float* __restrict__ W1,
    const float* __restrict__ b1, const float* __restrict__ w2,
    float* __restrict__ scores) {
  __shared__ float4 As[1152];
  __shared__ float4 Bs[1152];
  const int tid = threadIdx.x;
  const int tx = tid & 15, ty = tid >> 4;
  const long r0 = (long)blockIdx.x * 128;

  float acc[8][8] = {};
  for (int kk = 0; kk < 8; ++kk) {
    __syncthreads();
#pragma unroll
    for (int i = 0; i < 4; ++i) {
      const int q = tid + i * 256;
      const int row = q >> 3, kq = q & 7;
      const ushort4 uv = *(const ushort4*)&h1b[(r0 + row) * 256 + kk * 32 + kq * 4];
      As[row * 9 + kq] = bf4_to_f4(uv);
      Bs[row * 9 + kq] = *(const float4*)&W1[row * 256 + kk * 32 + kq * 4];
    }
    __syncthreads();
#pragma unroll
    for (int k4 = 0; k4 < 8; ++k4) {
      float4 bv[8];
#pragma unroll
      for (int jj = 0; jj < 8; ++jj) bv[jj] = Bs[(jj * 16 + tx) * 9 + k4];
#pragma unroll
      for (int rr = 0; rr < 8; ++rr) {
        const float4 av = As[(rr * 16 + ty) * 9 + k4];
#pragma unroll
        for (int jj = 0; jj < 8; ++jj) acc[rr][jj] += dot4(av, bv[jj]);
      }
    }
  }
  float pr[8];
#pragma unroll
  for (int rr = 0; rr < 8; ++rr) {
    float s = 0.0f;
#pragma unroll
    for (int jj = 0; jj < 8; ++jj) {
      const int col = jj * 16 + tx;
      s += tanh_fast(acc[rr][jj] + b1[col]) * w2[col];
    }
    pr[rr] = s;
  }
#pragma unroll
  for (int m = 1; m < 16; m <<= 1) {
#pragma unroll
    for (int rr = 0; rr < 8; ++rr) pr[rr] += __shfl_xor(pr[rr], m, 64);
  }
  if (tx == 0) {
#pragma unroll
    for (int rr = 0; rr < 8; ++rr) scores[r0 + rr * 16 + ty] = pr[rr];
  }
}

// ---------------- softmax over T + ctx + MLP head, one block per batch ----------------
__global__ __launch_bounds__(256, 2) void head_kernel(
    const float* __restrict__ scores, const unsigned short* __restrict__ h1b,
    const float* __restrict__ fW1, const float* __restrict__ fb1,
    const float* __restrict__ fW2, const float* __restrict__ fb2,
    float* __restrict__ outp) {
  const int b = blockIdx.x, tid = threadIdx.x;
  __shared__ float wls[1000];
  __shared__ float red[8];
  __shared__ __align__(16) float ctx[256];
  __shared__ __align__(16) float hid[128];

  float sv[4];
  float mx = -1e30f;
#pragma unroll
  for (int i = 0; i < 4; ++i) {
    const int t = tid + i * 256;
    sv[i] = (t < 1000) ? scores[b * 1000 + t] : -1e30f;
    mx = fmaxf(mx, sv[i]);
  }
  for (int m = 32; m; m >>= 1) mx = fmaxf(mx, __shfl_xor(mx, m, 64));
  if ((tid & 63) == 0) red[tid >> 6] = mx;
  __syncthreads();
  mx = fmaxf(fmaxf(red[0], red[1]), fmaxf(red[2], red[3]));
  float se = 0.0f;
#pragma unroll
  for (int i = 0; i < 4; ++i) {
    const int t = tid + i * 256;
    if (t < 1000) {
      const float e = __expf(sv[i] - mx);
      wls[t] = e;
      se += e;
    }
  }
  for (int m = 32; m; m >>= 1) se += __shfl_xor(se, m, 64);
  if ((tid & 63) == 0) red[4 + (tid >> 6)] = se;
  __syncthreads();
  const float rinv = 1.0f / (red[4] + red[5] + red[6] + red[7]);

  float a = 0.0f;
  const unsigned short* hb = h1b + (long)b * T_ * 256 + tid;
  for (int t = 0; t < T_; ++t) a = fmaf(wls[t], bf2f(hb[t * 256]), a);
  ctx[tid] = a * rinv;
  __syncthreads();
  if (tid < 128) {
    float s = fb1[tid];
    const float4* wr = (const float4*)&fW1[tid * 256];
    const float4* cc = (const float4*)ctx;
#pragma unroll
    for (int f = 0; f < 64; ++f) s += dot4(wr[f], cc[f]);
    hid[tid] = fmaxf(s, 0.0f);
  }
  __syncthreads();
  if (tid < 8) {
    float s = fb2[tid];
    const float4* wr = (const float4*)&fW2[tid * 128];
    const float4* hh = (const float4*)hid;
#pragma unroll
    for (int f = 0; f < 32; ++f) s += dot4(wr[f], hh[f]);
    outp[b * 8 + tid] = s;
  }
}

extern "C" void kernel_launch(void* const* d_in, const int* in_sizes, int n_in,
                              void* d_out, int out_size, void* d_ws, size_t ws_size,
                              hipStream_t stream) {
  (void)in_sizes; (void)n_in; (void)out_size;
  const float* x       = (const float*)d_in[0];
  const float* ln_g    = (const float*)d_in[1];
  const float* ln_b    = (const float*)d_in[2];
  const float* Wih_f0  = (const float*)d_in[3];
  const float* Whh_f0  = (const float*)d_in[4];
  const float* bih_f0  = (const float*)d_in[5];
  const float* bhh_f0  = (const float*)d_in[6];
  const float* Wih_b0  = (const float*)d_in[7];
  const float* Whh_b0  = (const float*)d_in[8];
  const float* bih_b0  = (const float*)d_in[9];
  const float* bhh_b0  = (const float*)d_in[10];
  const float* Wih_f1  = (const float*)d_in[11];
  const float* Whh_f1  = (const float*)d_in[12];
  const float* bih_f1  = (const float*)d_in[13];
  const float* bhh_f1  = (const float*)d_in[14];
  const float* Wih_b1  = (const float*)d_in[15];
  const float* Whh_b1  = (const float*)d_in[16];
  const float* bih_b1  = (const float*)d_in[17];
  const float* bhh_b1  = (const float*)d_in[18];
  const float* attn_W1 = (const float*)d_in[19];
  const float* attn_b1 = (const float*)d_in[20];
  const float* attn_w2 = (const float*)d_in[21];
  const float* fc_W1   = (const float*)d_in[22];
  const float* fc_b1   = (const float*)d_in[23];
  const float* fc_W2   = (const float*)d_in[24];
  const float* fc_b2   = (const float*)d_in[25];

  // ---- workspace layout (bytes), adapted to ws_size ----
  char* base = (char*)d_ws;
  size_t off = 0;
  auto alloc = [&](size_t bytes) {
    char* p = base + off;
    off += (bytes + 255) & ~(size_t)255;
    return p;
  };
  float*          h0    = (float*)alloc(32768000ull * 4);          // 131.1 MB
  unsigned short* h1b   = (unsigned short*)alloc(32768000ull * 2); //  65.5 MB
  float*          state = (float*)alloc(65536ull * 4);             //   0.26 MB
  float*          scor  = (float*)alloc(128000ull * 4);            //   0.51 MB

  const size_t rem = (ws_size > off) ? (ws_size - off) : 0;
  static const int cands[16] = {1000, 500, 250, 200, 125, 100, 50, 40, 25, 20, 10, 8, 5, 4, 2, 1};
  int Tc = 0;
  for (int ci = 0; ci < 16; ++ci) {
    if (524288ull * (size_t)cands[ci] <= rem) { Tc = cands[ci]; break; }
  }
  if (Tc == 0) {  // workspace too small for any plan: clean numeric fail (diagnostic)
    bail_kernel<<<dim3(1), dim3(256), 0, stream>>>((float*)d_out, 1024);
    return;
  }
  float* xwf = (float*)(base + off);
  float* xwb = xwf + 65536L * Tc;

  rec0_kernel<<<dim3(256), dim3(512), 0, stream>>>(x, ln_g, ln_b,
                                                   Wih_f0, Whh_f0, bih_f0, bhh_f0,
                                                   Wih_b0, Whh_b0, bih_b0, bhh_b0, h0);
  const int nch = T_ / Tc;
  for (int ch = 0; ch < nch; ++ch) {
    const int t0f = ch * Tc;
    const int t0b = T_ - (ch + 1) * Tc;
    gemm_xw1<<<dim3(Tc, 8), dim3(256), 0, stream>>>(h0, Wih_f1, Wih_b1, xwf, xwb, Tc, t0f, t0b);
    rec1_kernel<<<dim3(256), dim3(512), 0, stream>>>(xwf, xwb, Whh_f1, bih_f1, bhh_f1,
                                                     Whh_b1, bih_b1, bhh_b1, h1b, state,
                                                     Tc, t0f, t0b, (ch == 0) ? 1 : 0);
  }
  score_kernel<<<dim3(1000), dim3(256), 0, stream>>>(h1b, attn_W1, attn_b1, attn_w2, scor);
  head_kernel<<<dim3(128), dim3(256), 0, stream>>>(scor, h1b, fc_W1, fc_b1, fc_W2, fc_b2,
                                                   (float*)d_out);
}